// Round 7
// baseline (380.331 us; speedup 1.0000x reference)
//
#include <hip/hip_runtime.h>

// Problem constants: B=32, T=1024, IN=1024, OUT=1024
// M = B*T = 32768, K = IN = 1024, N = OUT = 1024
#define M_DIM 32768
#define N_DIM 1024
#define K_DIM 1024
#define T_DIM 1024
#define B_DIM 32
#define TSUB 128          // timesteps per m-subtile
#define NSUB (T_DIM / TSUB)   // 8

typedef unsigned int uint32;
typedef __attribute__((ext_vector_type(8))) short short8;       // 8 bf16 (MFMA A/B frag)
typedef __attribute__((ext_vector_type(8))) unsigned short ushort8v;
typedef __attribute__((ext_vector_type(4))) float floatx4;      // MFMA C/D frag

__device__ __forceinline__ unsigned short f2bf(float f) {
    uint32 u = __float_as_uint(f);
    uint32 r = u + 0x7fffu + ((u >> 16) & 1u);
    return (unsigned short)(r >> 16);
}

__device__ __forceinline__ void async_load16(const void* g, void* s) {
    __builtin_amdgcn_global_load_lds(
        (const __attribute__((address_space(1))) void*)g,
        (__attribute__((address_space(3))) void*)s,
        16, 0, 0);
}

// ---------------------------------------------------------------------------
// Fused fp32 -> bf16 cast for A and W in one dispatch (R1/R4-verified).
// ---------------------------------------------------------------------------
__global__ void cast_f32_bf16_fused(const float* __restrict__ X,
                                    const float* __restrict__ Wt,
                                    unsigned short* __restrict__ dst,
                                    int nA8, int nTot8) {
    int i = blockIdx.x * blockDim.x + threadIdx.x;
    if (i < nTot8) {
        const float* src = (i < nA8) ? (X + (size_t)i * 8)
                                     : (Wt + (size_t)(i - nA8) * 8);
        float4 v0 = ((const float4*)src)[0];
        float4 v1 = ((const float4*)src)[1];
        ushort8v o;
        o[0] = f2bf(v0.x); o[1] = f2bf(v0.y); o[2] = f2bf(v0.z); o[3] = f2bf(v0.w);
        o[4] = f2bf(v1.x); o[5] = f2bf(v1.y); o[6] = f2bf(v1.z); o[7] = f2bf(v1.w);
        ((ushort8v*)dst)[i] = o;
    }
}

// ---------------------------------------------------------------------------
// FULLY-FUSED GEMM + leaky-integrator scan. One block = one (batch, 128-col
// slice); block iterates the 8 m-subtiles (128 timesteps each) in t-order:
//   1. R4-verified 128x128 BK=64 double-buffered MFMA GEMM (8 waves).
//   2. acc+bias -> LDS fp32 tile Ct[128][130] (pad: quad rows 8 banks apart).
//   3. Hierarchical scan: 4 segs x 32 t per column; pass-1 weighted sums,
//      LDS seg-carry exchange, pass-2 rescan + coalesced fp32 out writes.
//   4. Ucar[128] carries the running state to the next subtile.
// No C intermediate, no carry array, no scan_apply dispatch.
// XCD map: all 8 col-tiles of a batch land on one XCD (A-panel L2-shared).
// Next subtile's k-tile-0 staging issues BEFORE the scan (latency hidden).
// ---------------------------------------------------------------------------
#define STAGE_A(db, rbase, k0)                                            \
  { _Pragma("unroll")                                                     \
    for (int q = 0; q < 2; ++q) {                                         \
      int slot = q * 512 + tid;                                           \
      int row  = slot >> 3;                                               \
      int ch   = slot & 7;                                                \
      int sc   = ch ^ (row & 7);                                          \
      async_load16(Ag + (size_t)((rbase) + row) * K_DIM + (k0) + sc * 8,  \
                   &As[db][slot * 8]);                                    \
    } }

#define STAGE_B(db, k0)                                                   \
  { _Pragma("unroll")                                                     \
    for (int q = 0; q < 2; ++q) {                                         \
      int slot = q * 512 + tid;                                           \
      int row  = slot >> 3;                                               \
      int ch   = slot & 7;                                                \
      int sc   = ch ^ (row & 7);                                          \
      async_load16(Bg + (size_t)(bn0 + row) * K_DIM + (k0) + sc * 8,      \
                   &Bs[db][slot * 8]);                                    \
    } }

#define COMPUTE(db)                                                       \
  { _Pragma("unroll")                                                     \
    for (int ks = 0; ks < 2; ++ks) {                                      \
      short8 af[4], bfr[2];                                               \
      _Pragma("unroll")                                                   \
      for (int m = 0; m < 4; ++m) {                                       \
        int r = wm * 64 + m * 16 + l15;                                   \
        int c = ks * 4 + quad;                                            \
        af[m] = *(const short8*)&As[db][r * 64 + ((c ^ (r & 7)) * 8)];    \
      }                                                                   \
      _Pragma("unroll")                                                   \
      for (int n = 0; n < 2; ++n) {                                       \
        int rb = wn * 32 + n * 16 + l15;                                  \
        int c = ks * 4 + quad;                                            \
        bfr[n] = *(const short8*)&Bs[db][rb * 64 + ((c ^ (rb & 7)) * 8)]; \
      }                                                                   \
      _Pragma("unroll")                                                   \
      for (int m = 0; m < 4; ++m)                                         \
        _Pragma("unroll")                                                 \
        for (int n = 0; n < 2; ++n)                                       \
          acc[m][n] = __builtin_amdgcn_mfma_f32_16x16x32_bf16(            \
              af[m], bfr[n], acc[m][n], 0, 0, 0);                         \
    } }

__global__ __launch_bounds__(512) void gemm_scan(
    const unsigned short* __restrict__ Ag,  // [M, K] bf16
    const unsigned short* __restrict__ Bg,  // [N, K] bf16
    const float* __restrict__ bias,         // [N]
    const float* __restrict__ decay,        // [N]
    float* __restrict__ out) {              // [M, N] fp32
    __shared__ unsigned short As[2][128 * 64];   // 2 x 16 KB
    __shared__ unsigned short Bs[2][128 * 64];   // 2 x 16 KB
    __shared__ float Ct[128 * 130];              // 66.6 KB (padded)
    __shared__ float SS[512];                    // seg partial sums
    __shared__ float Ucar[128];                  // running scan state / col

    const int tid  = threadIdx.x;            // 0..511
    const int lane = tid & 63;
    const int l15  = lane & 15;
    const int quad = lane >> 4;
    const int wid  = tid >> 6;               // 0..7
    const int wm   = wid >> 2;               // 0..1 (64-row half)
    const int wn   = wid & 3;                // 0..3 (32-col quarter)

    // Block map: 256 blocks; XCD x hosts batches 4x..4x+3 (8 col-tiles each).
    const int L     = blockIdx.x;
    const int xcd   = L & 7;
    const int rr    = L >> 3;                // 0..31
    const int batch = xcd * 4 + (rr >> 3);
    const int bn0   = (rr & 7) * 128;

    // Scan-role constants (seg wave-uniform: seg = wid>>1)
    const int colx = tid & 127;
    const int seg  = tid >> 7;               // 0..3
    const float aS  = decay[bn0 + colx];
    const float c1S = 1.0f - aS;
    float a32 = aS;
#pragma unroll
    for (int i = 0; i < 5; ++i) a32 *= a32;  // aS^32
    float bbE[2];
#pragma unroll
    for (int n = 0; n < 2; ++n) bbE[n] = bias[bn0 + wn * 32 + n * 16 + l15];

    if (tid < 128) Ucar[tid] = 0.f;

    floatx4 acc[4][2];

    // Initial stage: subtile 0, k-tile 0 into buf 0.
    STAGE_A(0, batch * T_DIM, 0);
    STAGE_B(0, 0);

#pragma unroll 1
    for (int s = 0; s < NSUB; ++s) {
        const int rbase = batch * T_DIM + s * TSUB;
#pragma unroll
        for (int m = 0; m < 4; ++m)
#pragma unroll
            for (int n = 0; n < 2; ++n)
                acc[m][n] = (floatx4){0.f, 0.f, 0.f, 0.f};

        __syncthreads();   // buf0 staging complete (barrier drains vmcnt)

        // ---- R4-verified double-buffered K loop ----
#pragma unroll 1
        for (int kt = 0; kt < 16; kt += 2) {
            STAGE_A(1, rbase, (kt + 1) * 64);
            STAGE_B(1, (kt + 1) * 64);
            COMPUTE(0);
            __syncthreads();
            if (kt + 2 < 16) {
                STAGE_A(0, rbase, (kt + 2) * 64);
                STAGE_B(0, (kt + 2) * 64);
            }
            COMPUTE(1);
            __syncthreads();
        }

        // Prefetch next subtile's k-tile 0 (completes under the scan phase;
        // the scan's barriers drain vmcnt before the next K loop).
        if (s + 1 < NSUB) {
            STAGE_A(0, rbase + TSUB, 0);
            STAGE_B(0, 0);
        }

        // ---- epilogue: acc + bias -> Ct[t][col] fp32 ----
#pragma unroll
        for (int n = 0; n < 2; ++n) {
            int cL = wn * 32 + n * 16 + l15;
#pragma unroll
            for (int m = 0; m < 4; ++m) {
                int t0 = wm * 64 + m * 16 + quad * 4;
#pragma unroll
                for (int r2 = 0; r2 < 4; ++r2)
                    Ct[(t0 + r2) * 130 + cL] = acc[m][n][r2] + bbE[n];
            }
        }
        __syncthreads();

        // ---- pass 1: per-seg weighted sum S = sum_i aS^(31-i) * x_i ----
        float S = 0.f;
#pragma unroll
        for (int i = 0; i < 32; ++i)
            S = aS * S + Ct[(seg * 32 + i) * 130 + colx];
        SS[tid] = S;     // SS[seg*128 + colx]
        __syncthreads();

        // carry-in for my segment (wave-uniform trip count)
        float uin = Ucar[colx];
        for (int j = 0; j < seg; ++j)
            uin = a32 * uin + c1S * SS[j * 128 + colx];

        // ---- pass 2: rescan + coalesced fp32 out writes ----
        float uu = uin;
        size_t ob = (size_t)(rbase + seg * 32) * N_DIM + bn0 + colx;
#pragma unroll
        for (int i = 0; i < 32; ++i) {
            uu = aS * uu + c1S * Ct[(seg * 32 + i) * 130 + colx];
            out[ob + (size_t)i * N_DIM] = uu;
        }
        __syncthreads();
        if (seg == 3) Ucar[colx] = uu;   // next read is after many barriers
    }
}

// ---------------------------------------------------------------------------
// Fallbacks (only used if workspace too small for the bf16 path)
// ---------------------------------------------------------------------------
__global__ void scan_f32_inplace(float* __restrict__ buf,
                                 const float* __restrict__ decay) {
    int tid = blockIdx.x * 64 + threadIdx.x;
    int o = tid & (N_DIM - 1);
    size_t base = ((size_t)(tid >> 10) << 20) + o;
    float a = decay[o];
    float c = 1.f - a;
    float u = 0.f;
    for (int t0 = 0; t0 < 1024; t0 += 16) {
        float x[16];
#pragma unroll
        for (int k = 0; k < 16; ++k)
            x[k] = buf[base + (size_t)(t0 + k) * N_DIM];
#pragma unroll
        for (int k = 0; k < 16; ++k) {
            u = a * u + c * x[k];
            buf[base + (size_t)(t0 + k) * N_DIM] = u;
        }
    }
}

__global__ void gemm_naive(const float* __restrict__ X, const float* __restrict__ W,
                           const float* __restrict__ bias, float* __restrict__ out) {
    __shared__ float As[16][17], Bs[16][17];
    int tx = threadIdx.x, ty = threadIdx.y;
    int m0 = blockIdx.y * 16, n0 = blockIdx.x * 16;
    float acc = 0.f;
    for (int k0 = 0; k0 < K_DIM; k0 += 16) {
        As[ty][tx] = X[(size_t)(m0 + ty) * K_DIM + k0 + tx];
        Bs[ty][tx] = W[(size_t)(n0 + ty) * K_DIM + k0 + tx];
        __syncthreads();
#pragma unroll
        for (int kk = 0; kk < 16; ++kk) acc += As[ty][kk] * Bs[tx][kk];
        __syncthreads();
    }
    out[(size_t)(m0 + ty) * N_DIM + n0 + tx] = acc + bias[n0 + tx];
}

// ---------------------------------------------------------------------------
extern "C" void kernel_launch(void* const* d_in, const int* in_sizes, int n_in,
                              void* d_out, int out_size, void* d_ws, size_t ws_size,
                              hipStream_t stream) {
    const float* X     = (const float*)d_in[0];  // [B,T,IN]  = [M,K]
    const float* Wt    = (const float*)d_in[1];  // [OUT,IN]  = [N,K]
    const float* bias  = (const float*)d_in[2];  // [OUT]
    const float* decay = (const float*)d_in[3];  // [OUT]
    float* out = (float*)d_out;                  // [B,T,OUT] = [M,N]

    const size_t A_bytes = (size_t)M_DIM * K_DIM * 2;            // 64 MB
    const size_t W_bytes = (size_t)N_DIM * K_DIM * 2;            // 2 MB
    const size_t need    = A_bytes + W_bytes;                    // 66 MB

    const int nA8   = M_DIM * K_DIM / 8;
    const int nW8   = N_DIM * K_DIM / 8;
    const int nTot8 = nA8 + nW8;

    if (ws_size >= need) {
        unsigned short* Abf = (unsigned short*)d_ws;
        unsigned short* Wbf = (unsigned short*)((char*)d_ws + A_bytes);
        cast_f32_bf16_fused<<<(nTot8 + 255) / 256, 256, 0, stream>>>(X, Wt, Abf, nA8, nTot8);
        gemm_scan<<<B_DIM * (N_DIM / 128), 512, 0, stream>>>(
            Abf, Wbf, bias, decay, out);
    } else {
        gemm_naive<<<dim3(N_DIM / 16, M_DIM / 16), dim3(16, 16), 0, stream>>>(X, Wt, bias, out);
        scan_f32_inplace<<<512, 64, 0, stream>>>(out, decay);
    }
}